// Round 1
// baseline (120.245 us; speedup 1.0000x reference)
//
#include <hip/hip_runtime.h>

typedef __attribute__((ext_vector_type(8))) short bf16x8;
typedef __attribute__((ext_vector_type(4))) float f32x4;

// ---------- helpers ----------

__device__ __forceinline__ unsigned short f2bf(float f) {
    unsigned int u = __builtin_bit_cast(unsigned int, f);
    u += 0x7fffu + ((u >> 16) & 1u);
    return (unsigned short)(u >> 16);
}

__device__ __forceinline__ void g2lds16(const unsigned short* g, unsigned short* l) {
    __builtin_amdgcn_global_load_lds(
        (const __attribute__((address_space(1))) unsigned int*)g,
        (__attribute__((address_space(3))) unsigned int*)l, 16, 0, 0);
}

// ---------- f32 -> bf16 pack ----------

__global__ __launch_bounds__(256)
void pack_bf16_kernel(const float* __restrict__ in, unsigned short* __restrict__ out, int n4) {
    int i = blockIdx.x * 256 + threadIdx.x;
    if (i >= n4) return;
    float4 v = reinterpret_cast<const float4*>(in)[i];
    union { unsigned short s[4]; uint2 u; } o;
    o.s[0] = f2bf(v.x); o.s[1] = f2bf(v.y); o.s[2] = f2bf(v.z); o.s[3] = f2bf(v.w);
    reinterpret_cast<uint2*>(out)[i] = o.u;
}

// ---------- gamma power table: gpow[i] = gamma^i ----------

__global__ void gpow_kernel(const float* __restrict__ gamma, float* __restrict__ gpow, int T) {
    int i = blockIdx.x * blockDim.x + threadIdx.x;
    if (i < T) gpow[i] = powf(gamma[0], (float)i);
}

// ---------- vd[b*T+j] = dot(x[b,j,:], Wv[j,:]) + bv[j]  (one wave per row) ----------

__global__ __launch_bounds__(256)
void vdiag_kernel(const float* __restrict__ x, const float* __restrict__ Wv,
                  const float* __restrict__ bv, float* __restrict__ vd, int D) {
    int w = blockIdx.x * 4 + (threadIdx.x >> 6);
    int lane = threadIdx.x & 63;
    int b = w >> 10, j = w & 1023;
    const float* xr = x + (size_t)(b * 1024 + j) * D;
    const float* wr = Wv + (size_t)j * D;
    float s = 0.f;
    for (int e = lane; e < D; e += 64) s = fmaf(xr[e], wr[e], s);
    #pragma unroll
    for (int off = 32; off; off >>= 1) s += __shfl_down(s, off, 64);
    if (lane == 0) vd[w] = s + bv[j];
}

// ---------- NT GEMM: C[m,n] = sum_k A[m,k]*B[n,k]  (m97 structure, 128x128 tile) ----------
// A: (M x K) bf16 row-major, B: (N x K) bf16 row-major. ldC = N.
// BF16_OUT: C = bf16(relu(acc + bias[n])); else C = f32 acc.

template<bool BF16_OUT>
__global__ __launch_bounds__(256, 2)
void gemm_nt_kernel(const unsigned short* __restrict__ A, const unsigned short* __restrict__ B,
                    void* __restrict__ Cout, const float* __restrict__ bias,
                    int K, int N, long bsA, long bsB, long bsC) {
    __shared__ unsigned short lA[128 * 32];
    __shared__ unsigned short lB[128 * 32];

    const int tid = threadIdx.x;
    const int lane = tid & 63;
    const int wid = tid >> 6;
    const int wr = wid >> 1, wc = wid & 1;
    const int tileM = blockIdx.y * 128, tileN = blockIdx.x * 128;

    const unsigned short* Ab = A + blockIdx.z * bsA;
    const unsigned short* Bb = B + blockIdx.z * bsB;

    // staging coords: inst j writes LDS element (j*256+tid)*8; row=(j*256+tid)/4, col=(tid&3)*8
    const int r0 = tid >> 2;
    const int r1 = (tid + 256) >> 2;
    const int cc = (tid & 3) * 8;

    const int frow = lane & 15;
    const int fk = (lane >> 4) * 8;

    f32x4 acc[4][4];
    #pragma unroll
    for (int m = 0; m < 4; ++m)
        #pragma unroll
        for (int n = 0; n < 4; ++n)
            acc[m][n] = (f32x4){0.f, 0.f, 0.f, 0.f};

    for (int k0 = 0; k0 < K; k0 += 32) {
        g2lds16(Ab + (size_t)(tileM + r0) * K + (k0 + cc), &lA[tid * 8]);
        g2lds16(Ab + (size_t)(tileM + r1) * K + (k0 + cc), &lA[2048 + tid * 8]);
        g2lds16(Bb + (size_t)(tileN + r0) * K + (k0 + cc), &lB[tid * 8]);
        g2lds16(Bb + (size_t)(tileN + r1) * K + (k0 + cc), &lB[2048 + tid * 8]);
        __syncthreads();

        bf16x8 af[4], bfr[4];
        #pragma unroll
        for (int m = 0; m < 4; ++m)
            af[m] = *reinterpret_cast<const bf16x8*>(&lA[(wr * 64 + m * 16 + frow) * 32 + fk]);
        #pragma unroll
        for (int n = 0; n < 4; ++n)
            bfr[n] = *reinterpret_cast<const bf16x8*>(&lB[(wc * 64 + n * 16 + frow) * 32 + fk]);

        #pragma unroll
        for (int m = 0; m < 4; ++m)
            #pragma unroll
            for (int n = 0; n < 4; ++n)
                acc[m][n] = __builtin_amdgcn_mfma_f32_16x16x32_bf16(af[m], bfr[n], acc[m][n], 0, 0, 0);

        __syncthreads();
    }

    // C/D layout: col = lane&15, row = (lane>>4)*4 + i
    const int orow = (lane >> 4) * 4;
    const int ocol = lane & 15;

    if (BF16_OUT) {
        unsigned short* C = (unsigned short*)Cout + blockIdx.z * bsC;
        #pragma unroll
        for (int m = 0; m < 4; ++m)
            #pragma unroll
            for (int n = 0; n < 4; ++n) {
                int col = tileN + wc * 64 + n * 16 + ocol;
                float bia = bias[col];
                #pragma unroll
                for (int i = 0; i < 4; ++i) {
                    int row = tileM + wr * 64 + m * 16 + orow + i;
                    float v = acc[m][n][i] + bia;
                    v = v > 0.f ? v : 0.f;
                    C[(size_t)row * N + col] = f2bf(v);
                }
            }
    } else {
        float* C = (float*)Cout + blockIdx.z * bsC;
        #pragma unroll
        for (int m = 0; m < 4; ++m)
            #pragma unroll
            for (int n = 0; n < 4; ++n) {
                int col = tileN + wc * 64 + n * 16 + ocol;
                #pragma unroll
                for (int i = 0; i < 4; ++i) {
                    int row = tileM + wr * 64 + m * 16 + orow + i;
                    C[(size_t)row * N + col] = acc[m][n][i];
                }
            }
    }
}

// ---------- denom[r] = eps + sum_j C(t,j) * QK[r,j],  r = b*T + t ----------

__global__ __launch_bounds__(256)
void denom_kernel(const float* __restrict__ QK, const float* __restrict__ gamma,
                  const float* __restrict__ gpow, float* __restrict__ dnm) {
    __shared__ float red[256];
    int r = blockIdx.x;
    int t = r & 1023;
    const float* row = QK + (size_t)r * 1024;
    float g = gamma[0];
    float inv1mg = 1.0f / (1.0f - g);
    float c1 = g * inv1mg;
    float ct = (1.0f - g * gpow[t]) * inv1mg;
    float s = 0.f;
    for (int j = threadIdx.x; j < 1024; j += 256) {
        float C = (j <= t) ? ((float)(t - j + 1) + c1 * (1.0f - gpow[j]))
                           : (gpow[j - t] * ct);
        s += C * row[j];
    }
    red[threadIdx.x] = s;
    __syncthreads();
    #pragma unroll
    for (int off = 128; off; off >>= 1) {
        if (threadIdx.x < off) red[threadIdx.x] += red[threadIdx.x + off];
        __syncthreads();
    }
    if (threadIdx.x == 0) dnm[r] = red[0] + 1e-6f;
}

// ---------- out[r,j] = C(t,j) * vd[b,j] * QK[r,j] / dnm[r]  (in place on QK) ----------

__global__ __launch_bounds__(256)
void finalize_kernel(float* __restrict__ QK, const float* __restrict__ vd,
                     const float* __restrict__ dnm, const float* __restrict__ gamma,
                     const float* __restrict__ gpow) {
    int idx = blockIdx.x * 256 + threadIdx.x;   // one float4 per thread
    int r = idx >> 8;
    int q4 = idx & 255;
    int j0 = q4 * 4;
    int b = r >> 10, t = r & 1023;
    float g = gamma[0];
    float inv1mg = 1.0f / (1.0f - g);
    float c1 = g * inv1mg;
    float ct = (1.0f - g * gpow[t]) * inv1mg;
    float inv = 1.0f / dnm[r];

    float4 qk = reinterpret_cast<float4*>(QK + (size_t)r * 1024)[q4];
    float4 vv = reinterpret_cast<const float4*>(vd + b * 1024)[q4];

    float o[4];
    float qa[4] = {qk.x, qk.y, qk.z, qk.w};
    float va[4] = {vv.x, vv.y, vv.z, vv.w};
    #pragma unroll
    for (int c = 0; c < 4; ++c) {
        int j = j0 + c;
        float C = (j <= t) ? ((float)(t - j + 1) + c1 * (1.0f - gpow[j]))
                           : (gpow[j - t] * ct);
        o[c] = C * va[c] * qa[c] * inv;
    }
    float4 res = {o[0], o[1], o[2], o[3]};
    reinterpret_cast<float4*>(QK + (size_t)r * 1024)[q4] = res;
}

// ---------- launch ----------

extern "C" void kernel_launch(void* const* d_in, const int* in_sizes, int n_in,
                              void* d_out, int out_size, void* d_ws, size_t ws_size,
                              hipStream_t stream) {
    const float* x     = (const float*)d_in[0];
    const float* gamma = (const float*)d_in[1];
    const float* Wq    = (const float*)d_in[2];
    const float* bq    = (const float*)d_in[3];
    const float* Wk    = (const float*)d_in[4];
    const float* bk    = (const float*)d_in[5];
    const float* Wv    = (const float*)d_in[6];
    const float* bv    = (const float*)d_in[7];
    float* out = (float*)d_out;

    const int D = 1024, T = 1024;
    const int B = in_sizes[0] / (T * D);
    const int M = B * T;  // 4096

    char* ws = (char*)d_ws;
    size_t off = 0;
    unsigned short* xb  = (unsigned short*)(ws + off); off += (size_t)M * D * 2;
    unsigned short* wqb = (unsigned short*)(ws + off); off += (size_t)D * D * 2;
    unsigned short* wkb = (unsigned short*)(ws + off); off += (size_t)D * D * 2;
    unsigned short* qb  = (unsigned short*)(ws + off); off += (size_t)M * D * 2;
    unsigned short* kb  = (unsigned short*)(ws + off); off += (size_t)M * D * 2;
    float* vd   = (float*)(ws + off); off += (size_t)M * 4;
    float* dnm  = (float*)(ws + off); off += (size_t)M * 4;
    float* gpow = (float*)(ws + off); off += (size_t)T * 4;

    // 1. pack x, Wq, Wk to bf16
    pack_bf16_kernel<<<dim3(M * D / 4 / 256), 256, 0, stream>>>(x, xb, M * D / 4);
    pack_bf16_kernel<<<dim3(D * D / 4 / 256), 256, 0, stream>>>(Wq, wqb, D * D / 4);
    pack_bf16_kernel<<<dim3(D * D / 4 / 256), 256, 0, stream>>>(Wk, wkb, D * D / 4);

    // 2. gamma power table
    gpow_kernel<<<dim3(T / 256), 256, 0, stream>>>(gamma, gpow, T);

    // 3. v diagonal
    vdiag_kernel<<<dim3(M / 4), 256, 0, stream>>>(x, Wv, bv, vd, D);

    // 4. q = relu(x Wq^T + bq) -> bf16 ; k = relu(x Wk^T + bk) -> bf16
    gemm_nt_kernel<true><<<dim3(D / 128, M / 128, 1), 256, 0, stream>>>(
        xb, wqb, qb, bq, D, D, 0, 0, 0);
    gemm_nt_kernel<true><<<dim3(D / 128, M / 128, 1), 256, 0, stream>>>(
        xb, wkb, kb, bk, D, D, 0, 0, 0);

    // 5. QK[b] = q[b] k[b]^T  (f32, straight into d_out)
    gemm_nt_kernel<false><<<dim3(T / 128, T / 128, B), 256, 0, stream>>>(
        qb, kb, out, nullptr, D, T, (long)T * D, (long)T * D, (long)T * T);

    // 6. denom
    denom_kernel<<<dim3(M), 256, 0, stream>>>(out, gamma, gpow, dnm);

    // 7. finalize in place
    finalize_kernel<<<dim3((size_t)M * T / 4 / 256), 256, 0, stream>>>(out, vd, dnm, gamma, gpow);
}

// Round 2
// 81.559 us; speedup vs baseline: 1.4743x; 1.4743x over previous
//
#include <hip/hip_runtime.h>

typedef __attribute__((ext_vector_type(8))) short bf16x8;
typedef __attribute__((ext_vector_type(4))) float f32x4;

// ---------- helpers ----------

__device__ __forceinline__ unsigned short f2bf(float f) {
    unsigned int u = __builtin_bit_cast(unsigned int, f);
    u += 0x7fffu + ((u >> 16) & 1u);
    return (unsigned short)(u >> 16);
}

__device__ __forceinline__ void g2lds16(const unsigned short* g, unsigned short* l) {
    __builtin_amdgcn_global_load_lds(
        (const __attribute__((address_space(1))) unsigned int*)g,
        (__attribute__((address_space(3))) unsigned int*)l, 16, 0, 0);
}

// ---------- pack x, Wq, Wk -> bf16 in one dispatch ----------
// xb = bf16(x); wqk rows [0,1024) = Wq, rows [1024,2048) = Wk

__global__ __launch_bounds__(256)
void pack3_kernel(const float* __restrict__ x, const float* __restrict__ wq,
                  const float* __restrict__ wk, unsigned short* __restrict__ xb,
                  unsigned short* __restrict__ wqk, int n4x, int n4w) {
    int i = blockIdx.x * 256 + threadIdx.x;
    const float* src; unsigned short* dst; int idx;
    if (i < n4x)            { src = x;  dst = xb;  idx = i; }
    else if (i < n4x + n4w) { src = wq; dst = wqk; idx = i - n4x; }
    else                    { src = wk; dst = wqk + (size_t)n4w * 4; idx = i - n4x - n4w; }
    float4 v = reinterpret_cast<const float4*>(src)[idx];
    union { unsigned short s[4]; uint2 u; } o;
    o.s[0] = f2bf(v.x); o.s[1] = f2bf(v.y); o.s[2] = f2bf(v.z); o.s[3] = f2bf(v.w);
    reinterpret_cast<uint2*>(dst)[idx] = o.u;
}

// ---------- vd[b*T+j] = dot(x[b,j,:], Wv[j,:]) + bv[j] (one wave/row, float4) ----------

__global__ __launch_bounds__(256)
void vdiag_kernel(const float* __restrict__ x, const float* __restrict__ Wv,
                  const float* __restrict__ bv, float* __restrict__ vd) {
    int w = blockIdx.x * 4 + (threadIdx.x >> 6);
    int lane = threadIdx.x & 63;
    int b = w >> 10, j = w & 1023;
    const float4* xr = reinterpret_cast<const float4*>(x + (size_t)(b * 1024 + j) * 1024);
    const float4* wr = reinterpret_cast<const float4*>(Wv + (size_t)j * 1024);
    float s = 0.f;
    #pragma unroll
    for (int e = 0; e < 4; ++e) {
        float4 a = xr[lane + 64 * e], c = wr[lane + 64 * e];
        s += a.x * c.x + a.y * c.y + a.z * c.z + a.w * c.w;
    }
    #pragma unroll
    for (int off = 32; off; off >>= 1) s += __shfl_down(s, off, 64);
    if (lane == 0) vd[w] = s + bv[j];
}

// ---------- NT GEMM, 128x128 tile, 2-phase double-buffered LDS ----------
// MODE 0: A=xb (Mx1024), B=wqk (2048x1024). out col<1024 -> qb (relu+bq),
//         col>=1024 -> kb (relu+bk). bf16 outputs.
// MODE 1: A=qb[z], B=kb[z] (1024x1024 each). Writes num' = C(t,j)*vd*acc to
//         out[z], and denom partials dpart[(bx*2+wc)*Mtot + z*1024 + t].

template<int MODE>
__global__ __launch_bounds__(256, 2)
void gemm_kernel(const unsigned short* __restrict__ A, const unsigned short* __restrict__ Bm,
                 unsigned short* __restrict__ qb, unsigned short* __restrict__ kb,
                 const float* __restrict__ bq, const float* __restrict__ bk,
                 float* __restrict__ out, const float* __restrict__ vd,
                 float* __restrict__ dpart, const float* __restrict__ gammap,
                 int K, int Mtot) {
    __shared__ unsigned short lA[2][128 * 32];
    __shared__ unsigned short lB[2][128 * 32];

    const int tid = threadIdx.x;
    const int lane = tid & 63;
    const int wid = tid >> 6;
    const int wr = wid >> 1, wc = wid & 1;
    const int tileM = blockIdx.y * 128, tileN = blockIdx.x * 128;

    const long bsAB = (MODE == 1) ? (long)1024 * 1024 : 0;
    const unsigned short* Ab = A + blockIdx.z * bsAB;
    const unsigned short* Bb = Bm + blockIdx.z * bsAB;

    const int r0 = tid >> 2;
    const int r1 = (tid + 256) >> 2;
    const int cc = (tid & 3) * 8;
    const int frow = lane & 15;
    const int fk = (lane >> 4) * 8;

    f32x4 acc[4][4];
    #pragma unroll
    for (int m = 0; m < 4; ++m)
        #pragma unroll
        for (int n = 0; n < 4; ++n)
            acc[m][n] = (f32x4){0.f, 0.f, 0.f, 0.f};

    auto stage = [&](int buf, int k0) {
        g2lds16(Ab + (size_t)(tileM + r0) * K + (k0 + cc), &lA[buf][tid * 8]);
        g2lds16(Ab + (size_t)(tileM + r1) * K + (k0 + cc), &lA[buf][2048 + tid * 8]);
        g2lds16(Bb + (size_t)(tileN + r0) * K + (k0 + cc), &lB[buf][tid * 8]);
        g2lds16(Bb + (size_t)(tileN + r1) * K + (k0 + cc), &lB[buf][2048 + tid * 8]);
    };

    stage(0, 0);
    __syncthreads();
    int cur = 0;
    for (int k0 = 0; k0 < K; k0 += 32) {
        if (k0 + 32 < K) stage(cur ^ 1, k0 + 32);   // prefetch next tile (in flight over MFMA)

        bf16x8 af[4], bfr[4];
        #pragma unroll
        for (int m = 0; m < 4; ++m)
            af[m] = *reinterpret_cast<const bf16x8*>(&lA[cur][(wr * 64 + m * 16 + frow) * 32 + fk]);
        #pragma unroll
        for (int n = 0; n < 4; ++n)
            bfr[n] = *reinterpret_cast<const bf16x8*>(&lB[cur][(wc * 64 + n * 16 + frow) * 32 + fk]);

        #pragma unroll
        for (int m = 0; m < 4; ++m)
            #pragma unroll
            for (int n = 0; n < 4; ++n)
                acc[m][n] = __builtin_amdgcn_mfma_f32_16x16x32_bf16(af[m], bfr[n], acc[m][n], 0, 0, 0);

        __syncthreads();   // drains vmcnt for the prefetch + lgkm; next buf ready
        cur ^= 1;
    }

    // C/D fragment layout: col = lane&15, row = (lane>>4)*4 + i
    const int orow = (lane >> 4) * 4;
    const int ocol = lane & 15;

    if constexpr (MODE == 0) {
        const bool isQ = tileN < 1024;
        unsigned short* Cq = isQ ? qb : kb;
        const float* bias = isQ ? bq : bk;
        const int cb = tileN - (isQ ? 0 : 1024);
        #pragma unroll
        for (int n = 0; n < 4; ++n) {
            int col = cb + wc * 64 + n * 16 + ocol;
            float bia = bias[col];
            #pragma unroll
            for (int m = 0; m < 4; ++m) {
                #pragma unroll
                for (int i = 0; i < 4; ++i) {
                    int row = tileM + wr * 64 + m * 16 + orow + i;
                    float v = acc[m][n][i] + bia;
                    Cq[(size_t)row * 1024 + col] = f2bf(v > 0.f ? v : 0.f);
                }
            }
        }
    } else {
        float* ob = out + (size_t)blockIdx.z * 1024 * 1024;
        const float* vdb = vd + blockIdx.z * 1024;
        const float g = gammap[0];
        const float l2g = log2f(g);
        const float inv1mg = 1.f / (1.f - g);
        const float c1 = g * inv1mg;

        int jcol[4]; float gj[4], vdv[4];
        #pragma unroll
        for (int n = 0; n < 4; ++n) {
            jcol[n] = tileN + wc * 64 + n * 16 + ocol;
            gj[n] = exp2f((float)jcol[n] * l2g);
            vdv[n] = vdb[jcol[n]];
        }

        #pragma unroll
        for (int m = 0; m < 4; ++m) {
            #pragma unroll
            for (int i = 0; i < 4; ++i) {
                int t = tileM + wr * 64 + m * 16 + orow + i;
                float gt = exp2f((float)t * l2g);
                float ctf = (1.f - g * gt) * inv1mg;
                float s = 0.f;
                #pragma unroll
                for (int n = 0; n < 4; ++n) {
                    int j = jcol[n];
                    float Cfut = exp2f((float)(j - t) * l2g) * ctf;      // j > t
                    float Cpast = (float)(t - j + 1) + c1 * (1.f - gj[n]); // j <= t
                    float Cw = (j <= t) ? Cpast : Cfut;
                    float v = acc[m][n][i];
                    s += Cw * v;
                    ob[(size_t)t * 1024 + j] = Cw * vdv[n] * v;
                }
                // reduce s across the 16 lanes holding this row's 16 columns
                s += __shfl_xor(s, 1, 64);
                s += __shfl_xor(s, 2, 64);
                s += __shfl_xor(s, 4, 64);
                s += __shfl_xor(s, 8, 64);
                if ((lane & 15) == 0)
                    dpart[(size_t)(blockIdx.x * 2 + wc) * Mtot + blockIdx.z * 1024 + t] = s;
            }
        }
    }
}

// ---------- out[r,:] *= 1/(eps + sum_p dpart[p][r]); one row per block ----------

__global__ __launch_bounds__(256)
void scale_kernel(float* __restrict__ out, const float* __restrict__ dpart, int Mtot) {
    int r = blockIdx.x;
    float s = 1e-6f;
    #pragma unroll
    for (int p = 0; p < 16; ++p) s += dpart[(size_t)p * Mtot + r];
    float inv = 1.f / s;
    float4* row = reinterpret_cast<float4*>(out + (size_t)r * 1024);
    float4 v = row[threadIdx.x];
    v.x *= inv; v.y *= inv; v.z *= inv; v.w *= inv;
    row[threadIdx.x] = v;
}

// ---------- launch ----------

extern "C" void kernel_launch(void* const* d_in, const int* in_sizes, int n_in,
                              void* d_out, int out_size, void* d_ws, size_t ws_size,
                              hipStream_t stream) {
    const float* x     = (const float*)d_in[0];
    const float* gamma = (const float*)d_in[1];
    const float* Wq    = (const float*)d_in[2];
    const float* bq    = (const float*)d_in[3];
    const float* Wk    = (const float*)d_in[4];
    const float* bk    = (const float*)d_in[5];
    const float* Wv    = (const float*)d_in[6];
    const float* bv    = (const float*)d_in[7];
    float* out = (float*)d_out;

    const int D = 1024, T = 1024;
    const int B = in_sizes[0] / (T * D);
    const int M = B * T;  // 4096

    char* ws = (char*)d_ws;
    size_t off = 0;
    unsigned short* xb  = (unsigned short*)(ws + off); off += (size_t)M * D * 2;      // 8 MB
    unsigned short* wqk = (unsigned short*)(ws + off); off += (size_t)2 * D * D * 2;  // 4 MB
    unsigned short* qb  = (unsigned short*)(ws + off); off += (size_t)M * D * 2;      // 8 MB
    unsigned short* kb  = (unsigned short*)(ws + off); off += (size_t)M * D * 2;      // 8 MB
    float* vd    = (float*)(ws + off); off += (size_t)M * 4;                          // 16 KB
    float* dpart = (float*)(ws + off); off += (size_t)16 * M * 4;                     // 256 KB

    const int n4x = M * D / 4, n4w = D * D / 4;

    // 1. pack x, Wq, Wk -> bf16
    pack3_kernel<<<dim3((n4x + 2 * n4w) / 256), 256, 0, stream>>>(x, Wq, Wk, xb, wqk, n4x, n4w);

    // 2. v diagonal
    vdiag_kernel<<<dim3(M / 4), 256, 0, stream>>>(x, Wv, bv, vd);

    // 3. q = relu(x Wq^T + bq), k = relu(x Wk^T + bk) in one GEMM (N = 2048)
    gemm_kernel<0><<<dim3(2048 / 128, M / 128, 1), 256, 0, stream>>>(
        xb, wqk, qb, kb, bq, bk, nullptr, nullptr, nullptr, nullptr, D, M);

    // 4. QK = q k^T per batch, fused: out = C*vd*QK (num'), dpart = denom partials
    gemm_kernel<1><<<dim3(T / 128, T / 128, B), 256, 0, stream>>>(
        qb, kb, nullptr, nullptr, nullptr, nullptr, out, vd, dpart, gamma, D, M);

    // 5. row scale by 1/denom
    scale_kernel<<<dim3(M), 256, 0, stream>>>(out, dpart, M);
}

// Round 3
// 79.637 us; speedup vs baseline: 1.5099x; 1.0241x over previous
//
#include <hip/hip_runtime.h>

typedef __attribute__((ext_vector_type(8))) short bf16x8;
typedef __attribute__((ext_vector_type(4))) float f32x4;

// ---------- helpers ----------

__device__ __forceinline__ unsigned short f2bf(float f) {
    unsigned int u = __builtin_bit_cast(unsigned int, f);
    u += 0x7fffu + ((u >> 16) & 1u);
    return (unsigned short)(u >> 16);
}

__device__ __forceinline__ float bf2f(unsigned short s) {
    return __builtin_bit_cast(float, (unsigned int)s << 16);
}

__device__ __forceinline__ void g2lds16(const unsigned short* g, unsigned short* l) {
    __builtin_amdgcn_global_load_lds(
        (const __attribute__((address_space(1))) unsigned int*)g,
        (__attribute__((address_space(3))) unsigned int*)l, 16, 0, 0);
}

// ---------- pack x, Wq, Wk -> bf16 in one dispatch ----------

__global__ __launch_bounds__(256)
void pack3_kernel(const float* __restrict__ x, const float* __restrict__ wq,
                  const float* __restrict__ wk, unsigned short* __restrict__ xb,
                  unsigned short* __restrict__ wqk, int n4x, int n4w) {
    int i = blockIdx.x * 256 + threadIdx.x;
    const float* src; unsigned short* dst; int idx;
    if (i < n4x)            { src = x;  dst = xb;  idx = i; }
    else if (i < n4x + n4w) { src = wq; dst = wqk; idx = i - n4x; }
    else                    { src = wk; dst = wqk + (size_t)n4w * 4; idx = i - n4x - n4w; }
    float4 v = reinterpret_cast<const float4*>(src)[idx];
    union { unsigned short s[4]; uint2 u; } o;
    o.s[0] = f2bf(v.x); o.s[1] = f2bf(v.y); o.s[2] = f2bf(v.z); o.s[3] = f2bf(v.w);
    reinterpret_cast<uint2*>(dst)[idx] = o.u;
}

// ---------- vd[b*T+j] = dot(xb[b,j,:], Wv[j,:]) + bv[j] (one wave/row, bf16 x) ----------

__global__ __launch_bounds__(256)
void vdiag_kernel(const unsigned short* __restrict__ xb, const float* __restrict__ Wv,
                  const float* __restrict__ bv, float* __restrict__ vd) {
    int w = blockIdx.x * 4 + (threadIdx.x >> 6);
    int lane = threadIdx.x & 63;
    int b = w >> 10, j = w & 1023;
    const unsigned short* xr = xb + (size_t)(b * 1024 + j) * 1024;
    const float* wr = Wv + (size_t)j * 1024;
    float s = 0.f;
    #pragma unroll
    for (int e = 0; e < 2; ++e) {
        int base = e * 512 + lane * 8;
        bf16x8 xv = *reinterpret_cast<const bf16x8*>(xr + base);
        float4 w0 = *reinterpret_cast<const float4*>(wr + base);
        float4 w1 = *reinterpret_cast<const float4*>(wr + base + 4);
        s = fmaf(bf2f((unsigned short)xv[0]), w0.x, s);
        s = fmaf(bf2f((unsigned short)xv[1]), w0.y, s);
        s = fmaf(bf2f((unsigned short)xv[2]), w0.z, s);
        s = fmaf(bf2f((unsigned short)xv[3]), w0.w, s);
        s = fmaf(bf2f((unsigned short)xv[4]), w1.x, s);
        s = fmaf(bf2f((unsigned short)xv[5]), w1.y, s);
        s = fmaf(bf2f((unsigned short)xv[6]), w1.z, s);
        s = fmaf(bf2f((unsigned short)xv[7]), w1.w, s);
    }
    #pragma unroll
    for (int off = 32; off; off >>= 1) s += __shfl_down(s, off, 64);
    if (lane == 0) vd[w] = s + bv[j];
}

// ---------- NT GEMM, 128x128 tile, 2-phase double-buffered LDS ----------
// MODE 0: A=xb (Mx1024), B=wqk (2048x1024). col<1024 -> qb (relu+bq),
//         col>=1024 -> kb (relu+bk). bf16 outputs.
// MODE 1: A=qb[z], B=kb[z]. Writes num' = C(t,j)*vd*acc as BF16 to nmb[z],
//         and denom partials dpart[(bx*2+wc)*Mtot + z*1024 + t].

template<int MODE>
__global__ __launch_bounds__(256, 2)
void gemm_kernel(const unsigned short* __restrict__ A, const unsigned short* __restrict__ Bm,
                 unsigned short* __restrict__ qb, unsigned short* __restrict__ kb,
                 const float* __restrict__ bq, const float* __restrict__ bk,
                 unsigned short* __restrict__ nmb, const float* __restrict__ vd,
                 float* __restrict__ dpart, const float* __restrict__ gammap,
                 int K, int Mtot) {
    __shared__ unsigned short lA[2][128 * 32];
    __shared__ unsigned short lB[2][128 * 32];

    const int tid = threadIdx.x;
    const int lane = tid & 63;
    const int wid = tid >> 6;
    const int wr = wid >> 1, wc = wid & 1;
    const int tileM = blockIdx.y * 128, tileN = blockIdx.x * 128;

    const long bsAB = (MODE == 1) ? (long)1024 * 1024 : 0;
    const unsigned short* Ab = A + blockIdx.z * bsAB;
    const unsigned short* Bb = Bm + blockIdx.z * bsAB;

    const int r0 = tid >> 2;
    const int r1 = (tid + 256) >> 2;
    const int cc = (tid & 3) * 8;
    const int frow = lane & 15;
    const int fk = (lane >> 4) * 8;

    f32x4 acc[4][4];
    #pragma unroll
    for (int m = 0; m < 4; ++m)
        #pragma unroll
        for (int n = 0; n < 4; ++n)
            acc[m][n] = (f32x4){0.f, 0.f, 0.f, 0.f};

    auto stage = [&](int buf, int k0) {
        g2lds16(Ab + (size_t)(tileM + r0) * K + (k0 + cc), &lA[buf][tid * 8]);
        g2lds16(Ab + (size_t)(tileM + r1) * K + (k0 + cc), &lA[buf][2048 + tid * 8]);
        g2lds16(Bb + (size_t)(tileN + r0) * K + (k0 + cc), &lB[buf][tid * 8]);
        g2lds16(Bb + (size_t)(tileN + r1) * K + (k0 + cc), &lB[buf][2048 + tid * 8]);
    };

    stage(0, 0);
    __syncthreads();
    int cur = 0;
    for (int k0 = 0; k0 < K; k0 += 32) {
        if (k0 + 32 < K) stage(cur ^ 1, k0 + 32);   // prefetch next tile

        bf16x8 af[4], bfr[4];
        #pragma unroll
        for (int m = 0; m < 4; ++m)
            af[m] = *reinterpret_cast<const bf16x8*>(&lA[cur][(wr * 64 + m * 16 + frow) * 32 + fk]);
        #pragma unroll
        for (int n = 0; n < 4; ++n)
            bfr[n] = *reinterpret_cast<const bf16x8*>(&lB[cur][(wc * 64 + n * 16 + frow) * 32 + fk]);

        #pragma unroll
        for (int m = 0; m < 4; ++m)
            #pragma unroll
            for (int n = 0; n < 4; ++n)
                acc[m][n] = __builtin_amdgcn_mfma_f32_16x16x32_bf16(af[m], bfr[n], acc[m][n], 0, 0, 0);

        __syncthreads();
        cur ^= 1;
    }

    // C/D fragment layout: col = lane&15, row = (lane>>4)*4 + i
    const int orow = (lane >> 4) * 4;
    const int ocol = lane & 15;

    if constexpr (MODE == 0) {
        const bool isQ = tileN < 1024;
        unsigned short* Cq = isQ ? qb : kb;
        const float* bias = isQ ? bq : bk;
        const int cb = tileN - (isQ ? 0 : 1024);
        #pragma unroll
        for (int n = 0; n < 4; ++n) {
            int col = cb + wc * 64 + n * 16 + ocol;
            float bia = bias[col];
            #pragma unroll
            for (int m = 0; m < 4; ++m) {
                #pragma unroll
                for (int i = 0; i < 4; ++i) {
                    int row = tileM + wr * 64 + m * 16 + orow + i;
                    float v = acc[m][n][i] + bia;
                    Cq[(size_t)row * 1024 + col] = f2bf(v > 0.f ? v : 0.f);
                }
            }
        }
    } else {
        unsigned short* ob = nmb + (size_t)blockIdx.z * 1024 * 1024;
        const float* vdb = vd + blockIdx.z * 1024;
        const float g = gammap[0];
        const float l2g = log2f(g);
        const float inv1mg = 1.f / (1.f - g);
        const float c1 = g * inv1mg;

        int jcol[4]; float gj[4], vdv[4];
        #pragma unroll
        for (int n = 0; n < 4; ++n) {
            jcol[n] = tileN + wc * 64 + n * 16 + ocol;
            gj[n] = exp2f((float)jcol[n] * l2g);
            vdv[n] = vdb[jcol[n]];
        }

        #pragma unroll
        for (int m = 0; m < 4; ++m) {
            #pragma unroll
            for (int i = 0; i < 4; ++i) {
                int t = tileM + wr * 64 + m * 16 + orow + i;
                float gt = exp2f((float)t * l2g);
                float ctf = (1.f - g * gt) * inv1mg;
                float s = 0.f;
                #pragma unroll
                for (int n = 0; n < 4; ++n) {
                    int j = jcol[n];
                    float Cfut = exp2f((float)(j - t) * l2g) * ctf;       // j > t
                    float Cpast = (float)(t - j + 1) + c1 * (1.f - gj[n]); // j <= t
                    float Cw = (j <= t) ? Cpast : Cfut;
                    float v = acc[m][n][i];
                    s += Cw * v;
                    ob[(size_t)t * 1024 + j] = f2bf(Cw * vdv[n] * v);
                }
                s += __shfl_xor(s, 1, 64);
                s += __shfl_xor(s, 2, 64);
                s += __shfl_xor(s, 4, 64);
                s += __shfl_xor(s, 8, 64);
                if ((lane & 15) == 0)
                    dpart[(size_t)(blockIdx.x * 2 + wc) * Mtot + blockIdx.z * 1024 + t] = s;
            }
        }
    }
}

// ---------- out[r,:] = bf16 num'[r,:] / (eps + sum_p dpart[p][r]) ----------

__global__ __launch_bounds__(256)
void scale_kernel(const unsigned short* __restrict__ nmb, float* __restrict__ out,
                  const float* __restrict__ dpart, int Mtot) {
    int r = blockIdx.x;
    float s = 1e-6f;
    #pragma unroll
    for (int p = 0; p < 16; ++p) s += dpart[(size_t)p * Mtot + r];
    float inv = 1.f / s;
    const uint2* src = reinterpret_cast<const uint2*>(nmb + (size_t)r * 1024);
    float4* dst = reinterpret_cast<float4*>(out + (size_t)r * 1024);
    uint2 u = src[threadIdx.x];
    float4 v = { bf2f((unsigned short)(u.x & 0xffff)) * inv,
                 bf2f((unsigned short)(u.x >> 16))    * inv,
                 bf2f((unsigned short)(u.y & 0xffff)) * inv,
                 bf2f((unsigned short)(u.y >> 16))    * inv };
    dst[threadIdx.x] = v;
}

// ---------- launch ----------

extern "C" void kernel_launch(void* const* d_in, const int* in_sizes, int n_in,
                              void* d_out, int out_size, void* d_ws, size_t ws_size,
                              hipStream_t stream) {
    const float* x     = (const float*)d_in[0];
    const float* gamma = (const float*)d_in[1];
    const float* Wq    = (const float*)d_in[2];
    const float* bq    = (const float*)d_in[3];
    const float* Wk    = (const float*)d_in[4];
    const float* bk    = (const float*)d_in[5];
    const float* Wv    = (const float*)d_in[6];
    const float* bv    = (const float*)d_in[7];
    float* out = (float*)d_out;

    const int D = 1024, T = 1024;
    const int B = in_sizes[0] / (T * D);
    const int M = B * T;  // 4096

    char* ws = (char*)d_ws;
    size_t off = 0;
    unsigned short* xb  = (unsigned short*)(ws + off); off += (size_t)M * D * 2;      // 8 MB
    unsigned short* wqk = (unsigned short*)(ws + off); off += (size_t)2 * D * D * 2;  // 4 MB
    unsigned short* qb  = (unsigned short*)(ws + off); off += (size_t)M * D * 2;      // 8 MB
    unsigned short* kb  = (unsigned short*)(ws + off); off += (size_t)M * D * 2;      // 8 MB
    float* vd    = (float*)(ws + off); off += (size_t)M * 4;                          // 16 KB
    float* dpart = (float*)(ws + off); off += (size_t)16 * M * 4;                     // 256 KB
    unsigned short* nmb = xb;  // xb is dead after mode0; reuse as bf16 num' scratch

    const int n4x = M * D / 4, n4w = D * D / 4;

    // 1. pack x, Wq, Wk -> bf16
    pack3_kernel<<<dim3((n4x + 2 * n4w) / 256), 256, 0, stream>>>(x, Wq, Wk, xb, wqk, n4x, n4w);

    // 2. v diagonal (reads bf16 xb)
    vdiag_kernel<<<dim3(M / 4), 256, 0, stream>>>(xb, Wv, bv, vd);

    // 3. q = relu(x Wq^T + bq), k = relu(x Wk^T + bk) in one GEMM (N = 2048)
    gemm_kernel<0><<<dim3(2048 / 128, M / 128, 1), 256, 0, stream>>>(
        xb, wqk, qb, kb, bq, bk, nullptr, nullptr, nullptr, nullptr, D, M);

    // 4. QK = q k^T per batch, fused: nmb = bf16(C*vd*QK), dpart = denom partials
    gemm_kernel<1><<<dim3(T / 128, T / 128, B), 256, 0, stream>>>(
        qb, kb, nullptr, nullptr, nullptr, nullptr, nmb, vd, dpart, gamma, D, M);

    // 5. out = num' / denom
    scale_kernel<<<dim3(M), 256, 0, stream>>>(nmb, out, dpart, M);
}